// Round 2
// baseline (1793.082 us; speedup 1.0000x reference)
//
#include <hip/hip_runtime.h>

// CorrectAndSmooth on MI355X.
// N=100000 nodes, C=48 classes, E=1.6M edges, 10+10 propagation layers.
// CSR (dst-sorted) built per call; gather kernel: 12 threads/node, float4/thread.

constexpr int NN  = 100000;
constexpr int NC  = 48;
constexpr int NE  = 1600000;
constexpr int NTR = 10000;
constexpr int NVA = 10000;
constexpr float ALPHA1 = 0.979f;   // correction
constexpr float ALPHA2 = 0.756f;   // smoothing

// ---------- preprocessing ----------

__global__ void k_count(const int* __restrict__ dst, int* __restrict__ deg) {
    int e = blockIdx.x * blockDim.x + threadIdx.x;
    if (e < NE) atomicAdd(&deg[dst[e]], 1);
}

// single-block exclusive scan over NN entries (tiled Hillis-Steele)
__global__ void k_scan(const int* __restrict__ deg, int* __restrict__ rowp) {
    __shared__ int sh[1024];
    __shared__ int carry;
    int tid = threadIdx.x;
    if (tid == 0) carry = 0;
    __syncthreads();
    for (int base = 0; base < NN; base += 1024) {
        int i = base + tid;
        int v = (i < NN) ? deg[i] : 0;
        sh[tid] = v;
        __syncthreads();
        for (int off = 1; off < 1024; off <<= 1) {
            int t = (tid >= off) ? sh[tid - off] : 0;
            __syncthreads();
            sh[tid] += t;
            __syncthreads();
        }
        if (i < NN) rowp[i] = carry + sh[tid] - v;   // exclusive
        __syncthreads();
        if (tid == 1023) carry += sh[1023];
        __syncthreads();
    }
    if (tid == 0) rowp[NN] = carry;                  // == NE
}

__global__ void k_norm(const int* __restrict__ deg, float* __restrict__ norm) {
    int v = blockIdx.x * blockDim.x + threadIdx.x;
    if (v < NN) {
        int d = deg[v]; if (d < 1) d = 1;
        norm[v] = rsqrtf((float)d);
    }
}

__global__ void k_fill(const int* __restrict__ src, const int* __restrict__ dst,
                       const int* __restrict__ rowp, int* __restrict__ fill,
                       int* __restrict__ csr) {
    int e = blockIdx.x * blockDim.x + threadIdx.x;
    if (e < NE) {
        int d = dst[e];
        int p = atomicAdd(&fill[d], 1);
        csr[rowp[d] + p] = src[e];
    }
}

// ---------- error build + sigma ----------
// error[train_nid[j]] = onehot(y_true[j]) - y_soft[j]  (first NTR rows of y_soft!)
// last = (1-ALPHA1)*error ; sigma += sum |error|
__global__ void k_error(const float* __restrict__ y_soft, const int* __restrict__ y_true,
                        const int* __restrict__ train, float* __restrict__ err,
                        float* __restrict__ last, float* __restrict__ sig) {
    int t = blockIdx.x * blockDim.x + threadIdx.x;
    float a = 0.f;
    if (t < NTR * NC) {
        int j = t / NC, c = t % NC;
        float e = ((c == y_true[j]) ? 1.0f : 0.0f) - y_soft[(size_t)j * NC + c];
        int r = train[j];
        err[(size_t)r * NC + c]  = e;
        last[(size_t)r * NC + c] = (1.0f - ALPHA1) * e;
        a = fabsf(e);
    }
    for (int off = 32; off > 0; off >>= 1) a += __shfl_down(a, off, 64);
    if ((threadIdx.x & 63) == 0) atomicAdd(sig, a);
}

// ---------- propagation layer (fused norm-gather-clip) ----------
// yout[d] = clip(last[d] + alpha*norm[d] * sum_{e: dst=d} norm[src_e]*yin[src_e], lo, hi)
__global__ void k_gather(const float* __restrict__ yin, float* __restrict__ yout,
                         const float* __restrict__ last, const float* __restrict__ norm,
                         const int* __restrict__ rowp, const int* __restrict__ csr,
                         float alpha, float lo, float hi) {
    int t = blockIdx.x * blockDim.x + threadIdx.x;
    if (t >= NN * 12) return;
    int node = t / 12, ch = t % 12;
    int beg = rowp[node], end = rowp[node + 1];
    float ax = 0.f, ay = 0.f, az = 0.f, aw = 0.f;
    for (int k = beg; k < end; ++k) {
        int s = csr[k];
        float ns = norm[s];
        float4 v = *reinterpret_cast<const float4*>(yin + (size_t)s * NC + ch * 4);
        ax += ns * v.x; ay += ns * v.y; az += ns * v.z; aw += ns * v.w;
    }
    float nd = alpha * norm[node];
    float4 l = *reinterpret_cast<const float4*>(last + (size_t)node * NC + ch * 4);
    float4 o;
    o.x = fminf(fmaxf(l.x + nd * ax, lo), hi);
    o.y = fminf(fmaxf(l.y + nd * ay, lo), hi);
    o.z = fminf(fmaxf(l.z + nd * az, lo), hi);
    o.w = fminf(fmaxf(l.w + nd * aw, lo), hi);
    *reinterpret_cast<float4*>(yout + (size_t)node * NC + ch * 4) = o;
}

// ---------- scale prep ----------
__global__ void k_rowabs(const float* __restrict__ se, float* __restrict__ rowabs) {
    int v = blockIdx.x * blockDim.x + threadIdx.x;
    if (v >= NN) return;
    const float4* p = reinterpret_cast<const float4*>(se + (size_t)v * NC);
    float s = 0.f;
#pragma unroll
    for (int k = 0; k < 12; ++k) {
        float4 x = p[k];
        s += fabsf(x.x) + fabsf(x.y) + fabsf(x.z) + fabsf(x.w);
    }
    rowabs[v] = s;
}

__device__ __forceinline__ int cat_at(int i, const int* __restrict__ tr,
                                      const int* __restrict__ va, const int* __restrict__ te) {
    if (i < NTR)        return tr[i];
    if (i < NTR + NVA)  return va[i - NTR];
    return te[i - NTR - NVA];
}

// result[i] = y_soft[i] + scale(i)*se[cat[i]] (NaN -> y_soft[i])
// y_all[cat[i]] = (i<NTR) ? onehot(y_true[i]) : result[i] ; last = (1-ALPHA2)*y_all
__global__ void k_phaseD(const float* __restrict__ se, const float* __restrict__ y_soft,
                         const float* __restrict__ rowabs, const float* __restrict__ sig,
                         const int* __restrict__ y_true,
                         const int* __restrict__ tr, const int* __restrict__ va,
                         const int* __restrict__ te,
                         float* __restrict__ y_all, float* __restrict__ last) {
    int t = blockIdx.x * blockDim.x + threadIdx.x;
    if (t >= NN * 12) return;
    int i = t / 12, ch = t % 12;
    int cid = cat_at(i, tr, va, te);
    float4 o;
    if (i < NTR) {
        int yt = y_true[i];
        o.x = (ch * 4 + 0 == yt) ? 1.f : 0.f;
        o.y = (ch * 4 + 1 == yt) ? 1.f : 0.f;
        o.z = (ch * 4 + 2 == yt) ? 1.f : 0.f;
        o.w = (ch * 4 + 3 == yt) ? 1.f : 0.f;
    } else {
        // scale = sigma/NTR / rowabs; sigma,rowabs >= 0 so scale is >=0, +inf, or NaN.
        // (isinf || >1000) ==> (>1000);  NaN propagates and is caught per-element below.
        float s = (sig[0] * (1.0f / NTR)) / rowabs[i];
        if (s > 1000.0f) s = 1.0f;
        float4 e  = *reinterpret_cast<const float4*>(se     + (size_t)cid * NC + ch * 4);
        float4 ys = *reinterpret_cast<const float4*>(y_soft + (size_t)i   * NC + ch * 4);
        o.x = ys.x + s * e.x; if (o.x != o.x) o.x = ys.x;
        o.y = ys.y + s * e.y; if (o.y != o.y) o.y = ys.y;
        o.z = ys.z + s * e.z; if (o.z != o.z) o.z = ys.z;
        o.w = ys.w + s * e.w; if (o.w != o.w) o.w = ys.w;
    }
    *reinterpret_cast<float4*>(y_all + (size_t)cid * NC + ch * 4) = o;
    float la = 1.0f - ALPHA2;
    float4 L; L.x = la * o.x; L.y = la * o.y; L.z = la * o.z; L.w = la * o.w;
    *reinterpret_cast<float4*>(last + (size_t)cid * NC + ch * 4) = L;
}

// out[i] = yin[cat[i]]
__global__ void k_outgather(const float* __restrict__ yin, float* __restrict__ out,
                            const int* __restrict__ tr, const int* __restrict__ va,
                            const int* __restrict__ te) {
    int t = blockIdx.x * blockDim.x + threadIdx.x;
    if (t >= NN * 12) return;
    int i = t / 12, ch = t % 12;
    int cid = cat_at(i, tr, va, te);
    float4 v = *reinterpret_cast<const float4*>(yin + (size_t)cid * NC + ch * 4);
    *reinterpret_cast<float4*>(out + (size_t)i * NC + ch * 4) = v;
}

extern "C" void kernel_launch(void* const* d_in, const int* in_sizes, int n_in,
                              void* d_out, int out_size, void* d_ws, size_t ws_size,
                              hipStream_t stream) {
    const float* y_soft = (const float*)d_in[0];
    const int*   y_true = (const int*)d_in[1];
    const int*   src    = (const int*)d_in[2];
    const int*   dst    = (const int*)d_in[3];
    const int*   tr     = (const int*)d_in[4];
    const int*   va     = (const int*)d_in[5];
    const int*   te     = (const int*)d_in[6];
    float* out = (float*)d_out;

    char* ws = (char*)d_ws;
    size_t off = 0;
    auto alloc = [&](size_t bytes) -> void* {
        void* p = ws + off;
        off += (bytes + 255) & ~(size_t)255;
        return p;
    };
    float* A      = (float*)alloc((size_t)NN * NC * 4);   // 19.2 MB
    float* last   = (float*)alloc((size_t)NN * NC * 4);   // 19.2 MB
    int*   csr    = (int*)  alloc((size_t)NE * 4);        // 6.4 MB
    int*   deg    = (int*)  alloc((size_t)NN * 4);
    int*   fill   = (int*)  alloc((size_t)NN * 4);
    int*   rowp   = (int*)  alloc((size_t)(NN + 1) * 4);
    float* norm   = (float*)alloc((size_t)NN * 4);
    float* rowabs = (float*)alloc((size_t)NN * 4);
    float* sig    = (float*)alloc(256);

    (void)hipMemsetAsync(deg,  0, (size_t)NN * 4, stream);
    (void)hipMemsetAsync(fill, 0, (size_t)NN * 4, stream);
    (void)hipMemsetAsync(A,    0, (size_t)NN * NC * 4, stream);
    (void)hipMemsetAsync(last, 0, (size_t)NN * NC * 4, stream);
    (void)hipMemsetAsync(sig,  0, 4, stream);

    k_count<<<NE / 256, 256, 0, stream>>>(dst, deg);
    k_scan<<<1, 1024, 0, stream>>>(deg, rowp);
    k_norm<<<(NN + 255) / 256, 256, 0, stream>>>(deg, norm);
    k_fill<<<NE / 256, 256, 0, stream>>>(src, dst, rowp, fill, csr);
    k_error<<<(NTR * NC) / 256, 256, 0, stream>>>(y_soft, y_true, tr, A, last, sig);

    const int GT = (NN * 12 + 255) / 256;

    // propagation 1: error -> smoothed_error (ends in A after 10 layers)
    float* cur = A; float* oth = out;
    for (int l = 0; l < 10; ++l) {
        k_gather<<<GT, 256, 0, stream>>>(cur, oth, last, norm, rowp, csr,
                                         ALPHA1, -1.f, 1.f);
        float* t2 = cur; cur = oth; oth = t2;
    }

    k_rowabs<<<(NN + 255) / 256, 256, 0, stream>>>(A, rowabs);
    k_phaseD<<<GT, 256, 0, stream>>>(A, y_soft, rowabs, sig, y_true,
                                     tr, va, te, out, last);

    // propagation 2: y_all (in d_out) -> final (ends in d_out after 10 layers)
    cur = out; oth = A;
    for (int l = 0; l < 10; ++l) {
        k_gather<<<GT, 256, 0, stream>>>(cur, oth, last, norm, rowp, csr,
                                         ALPHA2, 0.f, 1.f);
        float* t2 = cur; cur = oth; oth = t2;
    }

    // out[i] = final[cat[i]] — gather into `last`, then copy back to d_out
    k_outgather<<<GT, 256, 0, stream>>>(cur, last, tr, va, te);
    (void)hipMemcpyAsync(d_out, last, (size_t)NN * NC * 4, hipMemcpyDeviceToDevice, stream);
}

// Round 3
// 1615.369 us; speedup vs baseline: 1.1100x; 1.1100x over previous
//
#include <hip/hip_runtime.h>

// CorrectAndSmooth on MI355X.
// N=100000 nodes, C=48 classes, E=1.6M edges, 10+10 propagation layers.
// CSR (dst-sorted) built per call; gather kernel: 12 threads/node, float4/thread.
// R2: replaced 180us single-block scan with 3-kernel device-wide scan;
//     phaseD in-place -> dropped final D2D memcpy.

constexpr int NN  = 100000;
constexpr int NC  = 48;
constexpr int NE  = 1600000;
constexpr int NTR = 10000;
constexpr int NVA = 10000;
constexpr float ALPHA1 = 0.979f;   // correction
constexpr float ALPHA2 = 0.756f;   // smoothing

constexpr int SCAN_B = 1024;                       // elements per scan block
constexpr int NB     = (NN + SCAN_B - 1) / SCAN_B; // 98 scan blocks

// ---------- preprocessing ----------

__global__ void k_count(const int* __restrict__ dst, int* __restrict__ deg) {
    int e = blockIdx.x * blockDim.x + threadIdx.x;
    if (e < NE) atomicAdd(&deg[dst[e]], 1);
}

// pass 1: per-block sums of deg (256 thr, 4 elems/thr)
__global__ void k_bsum(const int* __restrict__ deg, int* __restrict__ bsum) {
    int base = blockIdx.x * SCAN_B + threadIdx.x * 4;
    int s = 0;
    if (base + 3 < NN) {
        int4 q = *reinterpret_cast<const int4*>(deg + base);
        s = q.x + q.y + q.z + q.w;
    } else {
#pragma unroll
        for (int i = 0; i < 4; ++i) if (base + i < NN) s += deg[base + i];
    }
    for (int o = 32; o > 0; o >>= 1) s += __shfl_down(s, o, 64);
    __shared__ int sh[4];
    if ((threadIdx.x & 63) == 0) sh[threadIdx.x >> 6] = s;
    __syncthreads();
    if (threadIdx.x == 0) bsum[blockIdx.x] = sh[0] + sh[1] + sh[2] + sh[3];
}

// pass 2: single-block exclusive scan of the NB (=98) block sums, in place
__global__ void k_bscan(int* __restrict__ bsum) {
    __shared__ int sh[128];
    int t = threadIdx.x;
    int v = (t < NB) ? bsum[t] : 0;
    sh[t] = v;
    __syncthreads();
    for (int o = 1; o < 128; o <<= 1) {
        int u = (t >= o) ? sh[t - o] : 0;
        __syncthreads();
        sh[t] += u;
        __syncthreads();
    }
    if (t < NB) bsum[t] = sh[t] - v;   // exclusive
}

// pass 3: per-block exclusive scan + block offset -> rowp
__global__ void k_scatter(const int* __restrict__ deg, const int* __restrict__ boff,
                          int* __restrict__ rowp) {
    int base = blockIdx.x * SCAN_B + threadIdx.x * 4;
    int v0 = 0, v1 = 0, v2 = 0, v3 = 0;
    if (base + 3 < NN) {
        int4 q = *reinterpret_cast<const int4*>(deg + base);
        v0 = q.x; v1 = q.y; v2 = q.z; v3 = q.w;
    } else {
        if (base     < NN) v0 = deg[base];
        if (base + 1 < NN) v1 = deg[base + 1];
        if (base + 2 < NN) v2 = deg[base + 2];
        if (base + 3 < NN) v3 = deg[base + 3];
    }
    int tsum = v0 + v1 + v2 + v3;
    int lane = threadIdx.x & 63, w = threadIdx.x >> 6;
    int inc = tsum;
    for (int o = 1; o < 64; o <<= 1) {
        int u = __shfl_up(inc, o, 64);
        if (lane >= o) inc += u;
    }
    __shared__ int wsum[4];
    if (lane == 63) wsum[w] = inc;
    __syncthreads();
    int woff = 0;
#pragma unroll
    for (int i = 0; i < 4; ++i) if (i < w) woff += wsum[i];
    int ex = boff[blockIdx.x] + woff + inc - tsum;  // exclusive prefix of elem0
    if (base     < NN) rowp[base]     = ex;
    if (base + 1 < NN) rowp[base + 1] = ex + v0;
    if (base + 2 < NN) rowp[base + 2] = ex + v0 + v1;
    if (base + 3 < NN) rowp[base + 3] = ex + v0 + v1 + v2;
    if (blockIdx.x == 0 && threadIdx.x == 0) rowp[NN] = NE;
}

__global__ void k_norm(const int* __restrict__ deg, float* __restrict__ norm) {
    int v = blockIdx.x * blockDim.x + threadIdx.x;
    if (v < NN) {
        int d = deg[v]; if (d < 1) d = 1;
        norm[v] = rsqrtf((float)d);
    }
}

__global__ void k_fill(const int* __restrict__ src, const int* __restrict__ dst,
                       const int* __restrict__ rowp, int* __restrict__ fill,
                       int* __restrict__ csr) {
    int e = blockIdx.x * blockDim.x + threadIdx.x;
    if (e < NE) {
        int d = dst[e];
        int p = atomicAdd(&fill[d], 1);
        csr[rowp[d] + p] = src[e];
    }
}

// ---------- error build + sigma ----------
__global__ void k_error(const float* __restrict__ y_soft, const int* __restrict__ y_true,
                        const int* __restrict__ train, float* __restrict__ err,
                        float* __restrict__ last, float* __restrict__ sig) {
    int t = blockIdx.x * blockDim.x + threadIdx.x;
    float a = 0.f;
    if (t < NTR * NC) {
        int j = t / NC, c = t % NC;
        float e = ((c == y_true[j]) ? 1.0f : 0.0f) - y_soft[(size_t)j * NC + c];
        int r = train[j];
        err[(size_t)r * NC + c]  = e;
        last[(size_t)r * NC + c] = (1.0f - ALPHA1) * e;
        a = fabsf(e);
    }
    for (int off = 32; off > 0; off >>= 1) a += __shfl_down(a, off, 64);
    if ((threadIdx.x & 63) == 0) atomicAdd(sig, a);
}

// ---------- propagation layer (fused norm-gather-clip) ----------
// yout[d] = clip(last[d] + alpha*norm[d] * sum_{e: dst=d} norm[src_e]*yin[src_e], lo, hi)
__global__ void k_gather(const float* __restrict__ yin, float* __restrict__ yout,
                         const float* __restrict__ last, const float* __restrict__ norm,
                         const int* __restrict__ rowp, const int* __restrict__ csr,
                         float alpha, float lo, float hi) {
    int t = blockIdx.x * blockDim.x + threadIdx.x;
    if (t >= NN * 12) return;
    int node = t / 12, ch = t % 12;
    int beg = rowp[node], end = rowp[node + 1];
    float ax = 0.f, ay = 0.f, az = 0.f, aw = 0.f;
    for (int k = beg; k < end; ++k) {
        int s = csr[k];
        float ns = norm[s];
        float4 v = *reinterpret_cast<const float4*>(yin + (size_t)s * NC + ch * 4);
        ax += ns * v.x; ay += ns * v.y; az += ns * v.z; aw += ns * v.w;
    }
    float nd = alpha * norm[node];
    float4 l = *reinterpret_cast<const float4*>(last + (size_t)node * NC + ch * 4);
    float4 o;
    o.x = fminf(fmaxf(l.x + nd * ax, lo), hi);
    o.y = fminf(fmaxf(l.y + nd * ay, lo), hi);
    o.z = fminf(fmaxf(l.z + nd * az, lo), hi);
    o.w = fminf(fmaxf(l.w + nd * aw, lo), hi);
    *reinterpret_cast<float4*>(yout + (size_t)node * NC + ch * 4) = o;
}

// ---------- scale prep ----------
__global__ void k_rowabs(const float* __restrict__ se, float* __restrict__ rowabs) {
    int v = blockIdx.x * blockDim.x + threadIdx.x;
    if (v >= NN) return;
    const float4* p = reinterpret_cast<const float4*>(se + (size_t)v * NC);
    float s = 0.f;
#pragma unroll
    for (int k = 0; k < 12; ++k) {
        float4 x = p[k];
        s += fabsf(x.x) + fabsf(x.y) + fabsf(x.z) + fabsf(x.w);
    }
    rowabs[v] = s;
}

__device__ __forceinline__ int cat_at(int i, const int* __restrict__ tr,
                                      const int* __restrict__ va, const int* __restrict__ te) {
    if (i < NTR)        return tr[i];
    if (i < NTR + NVA)  return va[i - NTR];
    return te[i - NTR - NVA];
}

// In-place: y_all == se (each thread reads then writes only its own (cid,ch) slice).
// result[i] = y_soft[i] + scale(i)*se[cat[i]] (NaN -> y_soft[i])
// y_all[cat[i]] = (i<NTR) ? onehot(y_true[i]) : result[i] ; last = (1-ALPHA2)*y_all
__global__ void k_phaseD(float* __restrict__ se_yall, const float* __restrict__ y_soft,
                         const float* __restrict__ rowabs, const float* __restrict__ sig,
                         const int* __restrict__ y_true,
                         const int* __restrict__ tr, const int* __restrict__ va,
                         const int* __restrict__ te,
                         float* __restrict__ last) {
    int t = blockIdx.x * blockDim.x + threadIdx.x;
    if (t >= NN * 12) return;
    int i = t / 12, ch = t % 12;
    int cid = cat_at(i, tr, va, te);
    float4 o;
    if (i < NTR) {
        int yt = y_true[i];
        o.x = (ch * 4 + 0 == yt) ? 1.f : 0.f;
        o.y = (ch * 4 + 1 == yt) ? 1.f : 0.f;
        o.z = (ch * 4 + 2 == yt) ? 1.f : 0.f;
        o.w = (ch * 4 + 3 == yt) ? 1.f : 0.f;
    } else {
        // scale >= 0 or +inf or NaN; (isinf || >1000) == (>1000), NaN caught below.
        float s = (sig[0] * (1.0f / NTR)) / rowabs[i];
        if (s > 1000.0f) s = 1.0f;
        float4 e  = *reinterpret_cast<const float4*>(se_yall + (size_t)cid * NC + ch * 4);
        float4 ys = *reinterpret_cast<const float4*>(y_soft  + (size_t)i   * NC + ch * 4);
        o.x = ys.x + s * e.x; if (o.x != o.x) o.x = ys.x;
        o.y = ys.y + s * e.y; if (o.y != o.y) o.y = ys.y;
        o.z = ys.z + s * e.z; if (o.z != o.z) o.z = ys.z;
        o.w = ys.w + s * e.w; if (o.w != o.w) o.w = ys.w;
    }
    *reinterpret_cast<float4*>(se_yall + (size_t)cid * NC + ch * 4) = o;
    float la = 1.0f - ALPHA2;
    float4 L; L.x = la * o.x; L.y = la * o.y; L.z = la * o.z; L.w = la * o.w;
    *reinterpret_cast<float4*>(last + (size_t)cid * NC + ch * 4) = L;
}

// out[i] = yin[cat[i]]
__global__ void k_outgather(const float* __restrict__ yin, float* __restrict__ out,
                            const int* __restrict__ tr, const int* __restrict__ va,
                            const int* __restrict__ te) {
    int t = blockIdx.x * blockDim.x + threadIdx.x;
    if (t >= NN * 12) return;
    int i = t / 12, ch = t % 12;
    int cid = cat_at(i, tr, va, te);
    float4 v = *reinterpret_cast<const float4*>(yin + (size_t)cid * NC + ch * 4);
    *reinterpret_cast<float4*>(out + (size_t)i * NC + ch * 4) = v;
}

extern "C" void kernel_launch(void* const* d_in, const int* in_sizes, int n_in,
                              void* d_out, int out_size, void* d_ws, size_t ws_size,
                              hipStream_t stream) {
    const float* y_soft = (const float*)d_in[0];
    const int*   y_true = (const int*)d_in[1];
    const int*   src    = (const int*)d_in[2];
    const int*   dst    = (const int*)d_in[3];
    const int*   tr     = (const int*)d_in[4];
    const int*   va     = (const int*)d_in[5];
    const int*   te     = (const int*)d_in[6];
    float* out = (float*)d_out;

    char* ws = (char*)d_ws;
    size_t off = 0;
    auto alloc = [&](size_t bytes) -> void* {
        void* p = ws + off;
        off += (bytes + 255) & ~(size_t)255;
        return p;
    };
    float* A      = (float*)alloc((size_t)NN * NC * 4);   // 19.2 MB
    float* last   = (float*)alloc((size_t)NN * NC * 4);   // 19.2 MB
    int*   csr    = (int*)  alloc((size_t)NE * 4);        // 6.4 MB
    int*   deg    = (int*)  alloc((size_t)NN * 4);
    int*   fill   = (int*)  alloc((size_t)NN * 4);
    int*   rowp   = (int*)  alloc((size_t)(NN + 1) * 4);
    float* norm   = (float*)alloc((size_t)NN * 4);
    float* rowabs = (float*)alloc((size_t)NN * 4);
    int*   bsum   = (int*)  alloc((size_t)NB * 4);
    float* sig    = (float*)alloc(256);

    (void)hipMemsetAsync(deg,  0, (size_t)NN * 4, stream);
    (void)hipMemsetAsync(fill, 0, (size_t)NN * 4, stream);
    (void)hipMemsetAsync(A,    0, (size_t)NN * NC * 4, stream);
    (void)hipMemsetAsync(last, 0, (size_t)NN * NC * 4, stream);
    (void)hipMemsetAsync(sig,  0, 4, stream);

    k_count  <<<NE / 256, 256, 0, stream>>>(dst, deg);
    k_bsum   <<<NB, 256, 0, stream>>>(deg, bsum);
    k_bscan  <<<1, 128, 0, stream>>>(bsum);
    k_scatter<<<NB, 256, 0, stream>>>(deg, bsum, rowp);
    k_norm   <<<(NN + 255) / 256, 256, 0, stream>>>(deg, norm);
    k_fill   <<<NE / 256, 256, 0, stream>>>(src, dst, rowp, fill, csr);
    k_error  <<<(NTR * NC) / 256, 256, 0, stream>>>(y_soft, y_true, tr, A, last, sig);

    const int GT = (NN * 12 + 255) / 256;

    // propagation 1: error -> smoothed_error (A -> ... -> A after 10 layers)
    float* cur = A; float* oth = out;
    for (int l = 0; l < 10; ++l) {
        k_gather<<<GT, 256, 0, stream>>>(cur, oth, last, norm, rowp, csr,
                                         ALPHA1, -1.f, 1.f);
        float* t2 = cur; cur = oth; oth = t2;
    }

    k_rowabs<<<(NN + 255) / 256, 256, 0, stream>>>(A, rowabs);
    // in-place: A := y_all; last := (1-ALPHA2)*y_all
    k_phaseD<<<GT, 256, 0, stream>>>(A, y_soft, rowabs, sig, y_true,
                                     tr, va, te, last);

    // propagation 2: A -> out -> ... -> A after 10 layers
    cur = A; oth = out;
    for (int l = 0; l < 10; ++l) {
        k_gather<<<GT, 256, 0, stream>>>(cur, oth, last, norm, rowp, csr,
                                         ALPHA2, 0.f, 1.f);
        float* t2 = cur; cur = oth; oth = t2;
    }

    // d_out[i] = A[cat[i]]
    k_outgather<<<GT, 256, 0, stream>>>(A, out, tr, va, te);
}

// Round 4
// 1055.507 us; speedup vs baseline: 1.6988x; 1.5304x over previous
//
#include <hip/hip_runtime.h>
#include <hip/hip_fp16.h>

// CorrectAndSmooth on MI355X.
// N=100000 nodes, C=48 classes, E=1.6M edges, 10+10 propagation layers.
// R3: fp16 ping-pong feature storage (96B/row), norm pre-folded into stored
//     features (no per-edge norm[s] load), 4x unrolled gather loop.

constexpr int NN  = 100000;
constexpr int NC  = 48;
constexpr int NE  = 1600000;
constexpr int NTR = 10000;
constexpr int NVA = 10000;
constexpr float ALPHA1 = 0.979f;   // correction
constexpr float ALPHA2 = 0.756f;   // smoothing

constexpr int SCAN_B = 1024;
constexpr int NB     = (NN + SCAN_B - 1) / SCAN_B;

union H4 { uint2 u; __half2 h[2]; };

__device__ __forceinline__ float4 h4f(uint2 q) {
    H4 t; t.u = q;
    float2 a = __half22float2(t.h[0]), b = __half22float2(t.h[1]);
    return make_float4(a.x, a.y, b.x, b.y);
}
__device__ __forceinline__ uint2 f4h(float4 v) {
    H4 t;
    t.h[0] = __float22half2_rn(make_float2(v.x, v.y));
    t.h[1] = __float22half2_rn(make_float2(v.z, v.w));
    return t.u;
}

// ---------- preprocessing ----------

__global__ void k_count(const int* __restrict__ dst, int* __restrict__ deg) {
    int e = blockIdx.x * blockDim.x + threadIdx.x;
    if (e < NE) atomicAdd(&deg[dst[e]], 1);
}

__global__ void k_bsum(const int* __restrict__ deg, int* __restrict__ bsum) {
    int base = blockIdx.x * SCAN_B + threadIdx.x * 4;
    int s = 0;
    if (base + 3 < NN) {
        int4 q = *reinterpret_cast<const int4*>(deg + base);
        s = q.x + q.y + q.z + q.w;
    } else {
#pragma unroll
        for (int i = 0; i < 4; ++i) if (base + i < NN) s += deg[base + i];
    }
    for (int o = 32; o > 0; o >>= 1) s += __shfl_down(s, o, 64);
    __shared__ int sh[4];
    if ((threadIdx.x & 63) == 0) sh[threadIdx.x >> 6] = s;
    __syncthreads();
    if (threadIdx.x == 0) bsum[blockIdx.x] = sh[0] + sh[1] + sh[2] + sh[3];
}

__global__ void k_bscan(int* __restrict__ bsum) {
    __shared__ int sh[128];
    int t = threadIdx.x;
    int v = (t < NB) ? bsum[t] : 0;
    sh[t] = v;
    __syncthreads();
    for (int o = 1; o < 128; o <<= 1) {
        int u = (t >= o) ? sh[t - o] : 0;
        __syncthreads();
        sh[t] += u;
        __syncthreads();
    }
    if (t < NB) bsum[t] = sh[t] - v;
}

__global__ void k_scatter(const int* __restrict__ deg, const int* __restrict__ boff,
                          int* __restrict__ rowp) {
    int base = blockIdx.x * SCAN_B + threadIdx.x * 4;
    int v0 = 0, v1 = 0, v2 = 0, v3 = 0;
    if (base + 3 < NN) {
        int4 q = *reinterpret_cast<const int4*>(deg + base);
        v0 = q.x; v1 = q.y; v2 = q.z; v3 = q.w;
    } else {
        if (base     < NN) v0 = deg[base];
        if (base + 1 < NN) v1 = deg[base + 1];
        if (base + 2 < NN) v2 = deg[base + 2];
        if (base + 3 < NN) v3 = deg[base + 3];
    }
    int tsum = v0 + v1 + v2 + v3;
    int lane = threadIdx.x & 63, w = threadIdx.x >> 6;
    int inc = tsum;
    for (int o = 1; o < 64; o <<= 1) {
        int u = __shfl_up(inc, o, 64);
        if (lane >= o) inc += u;
    }
    __shared__ int wsum[4];
    if (lane == 63) wsum[w] = inc;
    __syncthreads();
    int woff = 0;
#pragma unroll
    for (int i = 0; i < 4; ++i) if (i < w) woff += wsum[i];
    int ex = boff[blockIdx.x] + woff + inc - tsum;
    if (base     < NN) rowp[base]     = ex;
    if (base + 1 < NN) rowp[base + 1] = ex + v0;
    if (base + 2 < NN) rowp[base + 2] = ex + v0 + v1;
    if (base + 3 < NN) rowp[base + 3] = ex + v0 + v1 + v2;
    if (blockIdx.x == 0 && threadIdx.x == 0) rowp[NN] = NE;
}

__global__ void k_norm(const int* __restrict__ deg, float* __restrict__ norm) {
    int v = blockIdx.x * blockDim.x + threadIdx.x;
    if (v < NN) {
        int d = deg[v]; if (d < 1) d = 1;
        norm[v] = rsqrtf((float)d);
    }
}

__global__ void k_fill(const int* __restrict__ src, const int* __restrict__ dst,
                       const int* __restrict__ rowp, int* __restrict__ fill,
                       int* __restrict__ csr) {
    int e = blockIdx.x * blockDim.x + threadIdx.x;
    if (e < NE) {
        int d = dst[e];
        int p = atomicAdd(&fill[d], 1);
        csr[rowp[d] + p] = src[e];
    }
}

// ---------- error build + sigma ----------
// A[train[j]] = norm[train[j]] * (onehot - y_soft[j])   (pre-scaled fp16)
// last[train[j]] = (1-ALPHA1) * (onehot - y_soft[j])    (unscaled fp16)
__global__ void k_error(const float* __restrict__ y_soft, const int* __restrict__ y_true,
                        const int* __restrict__ train, const float* __restrict__ norm,
                        __half* __restrict__ A, __half* __restrict__ last,
                        float* __restrict__ sig) {
    int t = blockIdx.x * blockDim.x + threadIdx.x;
    float a = 0.f;
    if (t < NTR * NC) {
        int j = t / NC, c = t % NC;
        float e = ((c == y_true[j]) ? 1.0f : 0.0f) - y_soft[(size_t)j * NC + c];
        int r = train[j];
        A[(size_t)r * NC + c]    = __float2half(norm[r] * e);
        last[(size_t)r * NC + c] = __float2half((1.0f - ALPHA1) * e);
        a = fabsf(e);
    }
    for (int off = 32; off > 0; off >>= 1) a += __shfl_down(a, off, 64);
    if ((threadIdx.x & 63) == 0) atomicAdd(sig, a);
}

// ---------- propagation layer ----------
// yin holds u = norm .* y (pre-scaled). Per node d:
//   y_d = clip(last_d + alpha*norm_d * sum_{e:dst=d} u_src, lo, hi)
//   yout_d = PRE ? norm_d*y_d : y_d
template <bool PRE>
__global__ void k_gather(const __half* __restrict__ yin, __half* __restrict__ yout,
                         const __half* __restrict__ last, const float* __restrict__ norm,
                         const int* __restrict__ rowp, const int* __restrict__ csr,
                         float alpha, float lo, float hi) {
    int t = blockIdx.x * blockDim.x + threadIdx.x;
    if (t >= NN * 12) return;
    int node = t / 12, ch = (t % 12) * 4;
    int beg = rowp[node], end = rowp[node + 1];
    float ax = 0.f, ay = 0.f, az = 0.f, aw = 0.f;
    int k = beg;
    for (; k + 4 <= end; k += 4) {
        int s0 = csr[k], s1 = csr[k + 1], s2 = csr[k + 2], s3 = csr[k + 3];
        uint2 q0 = *reinterpret_cast<const uint2*>(yin + (size_t)s0 * NC + ch);
        uint2 q1 = *reinterpret_cast<const uint2*>(yin + (size_t)s1 * NC + ch);
        uint2 q2 = *reinterpret_cast<const uint2*>(yin + (size_t)s2 * NC + ch);
        uint2 q3 = *reinterpret_cast<const uint2*>(yin + (size_t)s3 * NC + ch);
        float4 v0 = h4f(q0), v1 = h4f(q1), v2 = h4f(q2), v3 = h4f(q3);
        ax += (v0.x + v1.x) + (v2.x + v3.x);
        ay += (v0.y + v1.y) + (v2.y + v3.y);
        az += (v0.z + v1.z) + (v2.z + v3.z);
        aw += (v0.w + v1.w) + (v2.w + v3.w);
    }
    for (; k < end; ++k) {
        int s = csr[k];
        float4 v = h4f(*reinterpret_cast<const uint2*>(yin + (size_t)s * NC + ch));
        ax += v.x; ay += v.y; az += v.z; aw += v.w;
    }
    float nd = alpha * norm[node];
    float4 l = h4f(*reinterpret_cast<const uint2*>(last + (size_t)node * NC + ch));
    float4 o;
    o.x = fminf(fmaxf(fmaf(nd, ax, l.x), lo), hi);
    o.y = fminf(fmaxf(fmaf(nd, ay, l.y), lo), hi);
    o.z = fminf(fmaxf(fmaf(nd, az, l.z), lo), hi);
    o.w = fminf(fmaxf(fmaf(nd, aw, l.w), lo), hi);
    if (PRE) {
        float w = norm[node];
        o.x *= w; o.y *= w; o.z *= w; o.w *= w;
    }
    *reinterpret_cast<uint2*>(yout + (size_t)node * NC + ch) = f4h(o);
}

// ---------- scale prep ----------
__global__ void k_rowabs(const __half* __restrict__ se, float* __restrict__ rowabs) {
    int v = blockIdx.x * blockDim.x + threadIdx.x;
    if (v >= NN) return;
    const uint2* p = reinterpret_cast<const uint2*>(se + (size_t)v * NC);
    float s = 0.f;
#pragma unroll
    for (int k = 0; k < 12; ++k) {
        float4 x = h4f(p[k]);
        s += fabsf(x.x) + fabsf(x.y) + fabsf(x.z) + fabsf(x.w);
    }
    rowabs[v] = s;
}

__device__ __forceinline__ int cat_at(int i, const int* __restrict__ tr,
                                      const int* __restrict__ va, const int* __restrict__ te) {
    if (i < NTR)        return tr[i];
    if (i < NTR + NVA)  return va[i - NTR];
    return te[i - NTR - NVA];
}

// In-place on A (unscaled smoothed_error in, pre-scaled y_all out).
// result[i] = y_soft[i] + scale(i)*se[cat[i]] (NaN -> y_soft[i])
// A[cat[i]] = norm[cat[i]] * ((i<NTR) ? onehot : result) ; last = (1-ALPHA2)*(...)
__global__ void k_phaseD(__half* __restrict__ se_yall, const float* __restrict__ y_soft,
                         const float* __restrict__ rowabs, const float* __restrict__ sig,
                         const int* __restrict__ y_true,
                         const int* __restrict__ tr, const int* __restrict__ va,
                         const int* __restrict__ te, const float* __restrict__ norm,
                         __half* __restrict__ last) {
    int t = blockIdx.x * blockDim.x + threadIdx.x;
    if (t >= NN * 12) return;
    int i = t / 12, ch = (t % 12) * 4;
    int cid = cat_at(i, tr, va, te);
    float4 o;
    if (i < NTR) {
        int yt = y_true[i];
        o.x = (ch + 0 == yt) ? 1.f : 0.f;
        o.y = (ch + 1 == yt) ? 1.f : 0.f;
        o.z = (ch + 2 == yt) ? 1.f : 0.f;
        o.w = (ch + 3 == yt) ? 1.f : 0.f;
    } else {
        // scale >= 0 or +inf or NaN; (isinf || >1000) == (>1000), NaN caught below.
        float s = (sig[0] * (1.0f / NTR)) / rowabs[i];
        if (s > 1000.0f) s = 1.0f;
        float4 e  = h4f(*reinterpret_cast<const uint2*>(se_yall + (size_t)cid * NC + ch));
        float4 ys = *reinterpret_cast<const float4*>(y_soft + (size_t)i * NC + ch);
        o.x = ys.x + s * e.x; if (o.x != o.x) o.x = ys.x;
        o.y = ys.y + s * e.y; if (o.y != o.y) o.y = ys.y;
        o.z = ys.z + s * e.z; if (o.z != o.z) o.z = ys.z;
        o.w = ys.w + s * e.w; if (o.w != o.w) o.w = ys.w;
    }
    float w = norm[cid];
    *reinterpret_cast<uint2*>(se_yall + (size_t)cid * NC + ch) =
        f4h(make_float4(o.x * w, o.y * w, o.z * w, o.w * w));
    float la = 1.0f - ALPHA2;
    *reinterpret_cast<uint2*>(last + (size_t)cid * NC + ch) =
        f4h(make_float4(la * o.x, la * o.y, la * o.z, la * o.w));
}

// out[i] = yin[cat[i]]  (fp16 -> f32)
__global__ void k_outgather(const __half* __restrict__ yin, float* __restrict__ out,
                            const int* __restrict__ tr, const int* __restrict__ va,
                            const int* __restrict__ te) {
    int t = blockIdx.x * blockDim.x + threadIdx.x;
    if (t >= NN * 12) return;
    int i = t / 12, ch = (t % 12) * 4;
    int cid = cat_at(i, tr, va, te);
    float4 v = h4f(*reinterpret_cast<const uint2*>(yin + (size_t)cid * NC + ch));
    *reinterpret_cast<float4*>(out + (size_t)i * NC + ch) = v;
}

extern "C" void kernel_launch(void* const* d_in, const int* in_sizes, int n_in,
                              void* d_out, int out_size, void* d_ws, size_t ws_size,
                              hipStream_t stream) {
    const float* y_soft = (const float*)d_in[0];
    const int*   y_true = (const int*)d_in[1];
    const int*   src    = (const int*)d_in[2];
    const int*   dst    = (const int*)d_in[3];
    const int*   tr     = (const int*)d_in[4];
    const int*   va     = (const int*)d_in[5];
    const int*   te     = (const int*)d_in[6];
    float* out = (float*)d_out;

    char* ws = (char*)d_ws;
    size_t off = 0;
    auto alloc = [&](size_t bytes) -> void* {
        void* p = ws + off;
        off += (bytes + 255) & ~(size_t)255;
        return p;
    };
    __half* A      = (__half*)alloc((size_t)NN * NC * 2);   // 9.6 MB
    __half* B      = (__half*)alloc((size_t)NN * NC * 2);   // 9.6 MB
    __half* last   = (__half*)alloc((size_t)NN * NC * 2);   // 9.6 MB
    int*    csr    = (int*)   alloc((size_t)NE * 4);        // 6.4 MB
    int*    deg    = (int*)   alloc((size_t)NN * 4);
    int*    fill   = (int*)   alloc((size_t)NN * 4);
    int*    rowp   = (int*)   alloc((size_t)(NN + 1) * 4);
    float*  norm   = (float*) alloc((size_t)NN * 4);
    float*  rowabs = (float*) alloc((size_t)NN * 4);
    int*    bsum   = (int*)   alloc((size_t)NB * 4);
    float*  sig    = (float*) alloc(256);

    (void)hipMemsetAsync(deg,  0, (size_t)NN * 4, stream);
    (void)hipMemsetAsync(fill, 0, (size_t)NN * 4, stream);
    (void)hipMemsetAsync(A,    0, (size_t)NN * NC * 2, stream);
    (void)hipMemsetAsync(last, 0, (size_t)NN * NC * 2, stream);
    (void)hipMemsetAsync(sig,  0, 4, stream);

    k_count  <<<NE / 256, 256, 0, stream>>>(dst, deg);
    k_bsum   <<<NB, 256, 0, stream>>>(deg, bsum);
    k_bscan  <<<1, 128, 0, stream>>>(bsum);
    k_scatter<<<NB, 256, 0, stream>>>(deg, bsum, rowp);
    k_norm   <<<(NN + 255) / 256, 256, 0, stream>>>(deg, norm);
    k_fill   <<<NE / 256, 256, 0, stream>>>(src, dst, rowp, fill, csr);
    k_error  <<<(NTR * NC) / 256, 256, 0, stream>>>(y_soft, y_true, tr, norm, A, last, sig);

    const int GT = (NN * 12 + 255) / 256;

    // propagation 1: A -> ... -> A (10 layers); last layer unscaled
    __half* cur = A; __half* oth = B;
    for (int l = 0; l < 10; ++l) {
        if (l < 9)
            k_gather<true><<<GT, 256, 0, stream>>>(cur, oth, last, norm, rowp, csr,
                                                   ALPHA1, -1.f, 1.f);
        else
            k_gather<false><<<GT, 256, 0, stream>>>(cur, oth, last, norm, rowp, csr,
                                                    ALPHA1, -1.f, 1.f);
        __half* t2 = cur; cur = oth; oth = t2;
    }

    k_rowabs<<<(NN + 255) / 256, 256, 0, stream>>>(A, rowabs);
    // in-place: A := norm .* y_all; last := (1-ALPHA2)*y_all
    k_phaseD<<<GT, 256, 0, stream>>>(A, y_soft, rowabs, sig, y_true,
                                     tr, va, te, norm, last);

    // propagation 2: A -> ... -> A (10 layers); last layer unscaled
    cur = A; oth = B;
    for (int l = 0; l < 10; ++l) {
        if (l < 9)
            k_gather<true><<<GT, 256, 0, stream>>>(cur, oth, last, norm, rowp, csr,
                                                   ALPHA2, 0.f, 1.f);
        else
            k_gather<false><<<GT, 256, 0, stream>>>(cur, oth, last, norm, rowp, csr,
                                                    ALPHA2, 0.f, 1.f);
        __half* t2 = cur; cur = oth; oth = t2;
    }

    // d_out[i] = A[cat[i]]
    k_outgather<<<GT, 256, 0, stream>>>(A, out, tr, va, te);
}

// Round 5
// 1020.158 us; speedup vs baseline: 1.7577x; 1.0347x over previous
//
#include <hip/hip_runtime.h>
#include <hip/hip_fp16.h>

// CorrectAndSmooth on MI355X.
// N=100000 nodes, C=48 classes, E=1.6M edges, 10+10 propagation layers.
// R4: CSR adjacency ordered by (dst, src-slice) with NS=3 slices (3.2MB fp16
//     features/slice) so concurrent gathers concentrate in an L2-resident
//     window. Gather loop itself unchanged (slices contiguous per row).

constexpr int NN  = 100000;
constexpr int NC  = 48;
constexpr int NE  = 1600000;
constexpr int NTR = 10000;
constexpr int NVA = 10000;
constexpr float ALPHA1 = 0.979f;   // correction
constexpr float ALPHA2 = 0.756f;   // smoothing

constexpr int NS = 3;                         // src slices
constexpr int SW = (NN + NS - 1) / NS;        // 33334 nodes/slice
constexpr int N3 = NN * NS;                   // 300000 (dst,slice) cells
constexpr int SCAN_B = 1024;
constexpr int NB3 = (N3 + SCAN_B - 1) / SCAN_B;  // 293

union H4 { uint2 u; __half2 h[2]; };

__device__ __forceinline__ float4 h4f(uint2 q) {
    H4 t; t.u = q;
    float2 a = __half22float2(t.h[0]), b = __half22float2(t.h[1]);
    return make_float4(a.x, a.y, b.x, b.y);
}
__device__ __forceinline__ uint2 f4h(float4 v) {
    H4 t;
    t.h[0] = __float22half2_rn(make_float2(v.x, v.y));
    t.h[1] = __float22half2_rn(make_float2(v.z, v.w));
    return t.u;
}

// ---------- preprocessing ----------

// deg3[d*NS + src/SW]++
__global__ void k_count3(const int* __restrict__ src, const int* __restrict__ dst,
                         int* __restrict__ deg3) {
    int e = blockIdx.x * blockDim.x + threadIdx.x;
    if (e < NE) {
        int d = dst[e], s = src[e] / SW;
        atomicAdd(&deg3[d * NS + s], 1);
    }
}

// pass 1: per-block sums of deg3 (256 thr, 4 elems/thr)
__global__ void k_bsum(const int* __restrict__ deg3, int* __restrict__ bsum) {
    int base = blockIdx.x * SCAN_B + threadIdx.x * 4;
    int s = 0;
    if (base + 3 < N3) {
        int4 q = *reinterpret_cast<const int4*>(deg3 + base);
        s = q.x + q.y + q.z + q.w;
    } else {
#pragma unroll
        for (int i = 0; i < 4; ++i) if (base + i < N3) s += deg3[base + i];
    }
    for (int o = 32; o > 0; o >>= 1) s += __shfl_down(s, o, 64);
    __shared__ int sh[4];
    if ((threadIdx.x & 63) == 0) sh[threadIdx.x >> 6] = s;
    __syncthreads();
    if (threadIdx.x == 0) bsum[blockIdx.x] = sh[0] + sh[1] + sh[2] + sh[3];
}

// pass 2: single-block exclusive scan of NB3 (=293) block sums, in place
__global__ void k_bscan(int* __restrict__ bsum) {
    __shared__ int sh[512];
    int t = threadIdx.x;
    int v = (t < NB3) ? bsum[t] : 0;
    sh[t] = v;
    __syncthreads();
    for (int o = 1; o < 512; o <<= 1) {
        int u = (t >= o) ? sh[t - o] : 0;
        __syncthreads();
        sh[t] += u;
        __syncthreads();
    }
    if (t < NB3) bsum[t] = sh[t] - v;   // exclusive
}

// pass 3: per-block exclusive scan + block offset -> rowp3
__global__ void k_scatter(const int* __restrict__ deg3, const int* __restrict__ boff,
                          int* __restrict__ rowp3) {
    int base = blockIdx.x * SCAN_B + threadIdx.x * 4;
    int v0 = 0, v1 = 0, v2 = 0, v3 = 0;
    if (base + 3 < N3) {
        int4 q = *reinterpret_cast<const int4*>(deg3 + base);
        v0 = q.x; v1 = q.y; v2 = q.z; v3 = q.w;
    } else {
        if (base     < N3) v0 = deg3[base];
        if (base + 1 < N3) v1 = deg3[base + 1];
        if (base + 2 < N3) v2 = deg3[base + 2];
        if (base + 3 < N3) v3 = deg3[base + 3];
    }
    int tsum = v0 + v1 + v2 + v3;
    int lane = threadIdx.x & 63, w = threadIdx.x >> 6;
    int inc = tsum;
    for (int o = 1; o < 64; o <<= 1) {
        int u = __shfl_up(inc, o, 64);
        if (lane >= o) inc += u;
    }
    __shared__ int wsum[4];
    if (lane == 63) wsum[w] = inc;
    __syncthreads();
    int woff = 0;
#pragma unroll
    for (int i = 0; i < 4; ++i) if (i < w) woff += wsum[i];
    int ex = boff[blockIdx.x] + woff + inc - tsum;
    if (base     < N3) rowp3[base]     = ex;
    if (base + 1 < N3) rowp3[base + 1] = ex + v0;
    if (base + 2 < N3) rowp3[base + 2] = ex + v0 + v1;
    if (base + 3 < N3) rowp3[base + 3] = ex + v0 + v1 + v2;
    if (blockIdx.x == 0 && threadIdx.x == 0) rowp3[N3] = NE;
}

// norm[v] = rsqrt(max(deg,1)); deg from rowp3 row extent
__global__ void k_norm(const int* __restrict__ rowp3, float* __restrict__ norm) {
    int v = blockIdx.x * blockDim.x + threadIdx.x;
    if (v < NN) {
        int d = rowp3[(v + 1) * NS] - rowp3[v * NS];
        if (d < 1) d = 1;
        norm[v] = rsqrtf((float)d);
    }
}

__global__ void k_fill3(const int* __restrict__ src, const int* __restrict__ dst,
                        const int* __restrict__ rowp3, int* __restrict__ fill3,
                        int* __restrict__ csr) {
    int e = blockIdx.x * blockDim.x + threadIdx.x;
    if (e < NE) {
        int sv = src[e];
        int cell = dst[e] * NS + sv / SW;
        int p = atomicAdd(&fill3[cell], 1);
        csr[rowp3[cell] + p] = sv;
    }
}

// ---------- error build + sigma ----------
// A[train[j]] = norm[train[j]] * (onehot - y_soft[j])   (pre-scaled fp16)
// last[train[j]] = (1-ALPHA1) * (onehot - y_soft[j])    (unscaled fp16)
__global__ void k_error(const float* __restrict__ y_soft, const int* __restrict__ y_true,
                        const int* __restrict__ train, const float* __restrict__ norm,
                        __half* __restrict__ A, __half* __restrict__ last,
                        float* __restrict__ sig) {
    int t = blockIdx.x * blockDim.x + threadIdx.x;
    float a = 0.f;
    if (t < NTR * NC) {
        int j = t / NC, c = t % NC;
        float e = ((c == y_true[j]) ? 1.0f : 0.0f) - y_soft[(size_t)j * NC + c];
        int r = train[j];
        A[(size_t)r * NC + c]    = __float2half(norm[r] * e);
        last[(size_t)r * NC + c] = __float2half((1.0f - ALPHA1) * e);
        a = fabsf(e);
    }
    for (int off = 32; off > 0; off >>= 1) a += __shfl_down(a, off, 64);
    if ((threadIdx.x & 63) == 0) atomicAdd(sig, a);
}

// ---------- propagation layer ----------
// yin holds u = norm .* y (pre-scaled). Per node d:
//   y_d = clip(last_d + alpha*norm_d * sum_{e:dst=d} u_src, lo, hi)
//   yout_d = PRE ? norm_d*y_d : y_d
template <bool PRE>
__global__ void k_gather(const __half* __restrict__ yin, __half* __restrict__ yout,
                         const __half* __restrict__ last, const float* __restrict__ norm,
                         const int* __restrict__ rowp3, const int* __restrict__ csr,
                         float alpha, float lo, float hi) {
    int t = blockIdx.x * blockDim.x + threadIdx.x;
    if (t >= NN * 12) return;
    int node = t / 12, ch = (t % 12) * 4;
    int beg = rowp3[node * NS], end = rowp3[node * NS + NS];
    float ax = 0.f, ay = 0.f, az = 0.f, aw = 0.f;
    int k = beg;
    for (; k + 4 <= end; k += 4) {
        int s0 = csr[k], s1 = csr[k + 1], s2 = csr[k + 2], s3 = csr[k + 3];
        uint2 q0 = *reinterpret_cast<const uint2*>(yin + (size_t)s0 * NC + ch);
        uint2 q1 = *reinterpret_cast<const uint2*>(yin + (size_t)s1 * NC + ch);
        uint2 q2 = *reinterpret_cast<const uint2*>(yin + (size_t)s2 * NC + ch);
        uint2 q3 = *reinterpret_cast<const uint2*>(yin + (size_t)s3 * NC + ch);
        float4 v0 = h4f(q0), v1 = h4f(q1), v2 = h4f(q2), v3 = h4f(q3);
        ax += (v0.x + v1.x) + (v2.x + v3.x);
        ay += (v0.y + v1.y) + (v2.y + v3.y);
        az += (v0.z + v1.z) + (v2.z + v3.z);
        aw += (v0.w + v1.w) + (v2.w + v3.w);
    }
    for (; k < end; ++k) {
        int s = csr[k];
        float4 v = h4f(*reinterpret_cast<const uint2*>(yin + (size_t)s * NC + ch));
        ax += v.x; ay += v.y; az += v.z; aw += v.w;
    }
    float nd = alpha * norm[node];
    float4 l = h4f(*reinterpret_cast<const uint2*>(last + (size_t)node * NC + ch));
    float4 o;
    o.x = fminf(fmaxf(fmaf(nd, ax, l.x), lo), hi);
    o.y = fminf(fmaxf(fmaf(nd, ay, l.y), lo), hi);
    o.z = fminf(fmaxf(fmaf(nd, az, l.z), lo), hi);
    o.w = fminf(fmaxf(fmaf(nd, aw, l.w), lo), hi);
    if (PRE) {
        float w = norm[node];
        o.x *= w; o.y *= w; o.z *= w; o.w *= w;
    }
    *reinterpret_cast<uint2*>(yout + (size_t)node * NC + ch) = f4h(o);
}

// ---------- scale prep ----------
__global__ void k_rowabs(const __half* __restrict__ se, float* __restrict__ rowabs) {
    int v = blockIdx.x * blockDim.x + threadIdx.x;
    if (v >= NN) return;
    const uint2* p = reinterpret_cast<const uint2*>(se + (size_t)v * NC);
    float s = 0.f;
#pragma unroll
    for (int k = 0; k < 12; ++k) {
        float4 x = h4f(p[k]);
        s += fabsf(x.x) + fabsf(x.y) + fabsf(x.z) + fabsf(x.w);
    }
    rowabs[v] = s;
}

__device__ __forceinline__ int cat_at(int i, const int* __restrict__ tr,
                                      const int* __restrict__ va, const int* __restrict__ te) {
    if (i < NTR)        return tr[i];
    if (i < NTR + NVA)  return va[i - NTR];
    return te[i - NTR - NVA];
}

// In-place on A (unscaled smoothed_error in, pre-scaled y_all out).
__global__ void k_phaseD(__half* __restrict__ se_yall, const float* __restrict__ y_soft,
                         const float* __restrict__ rowabs, const float* __restrict__ sig,
                         const int* __restrict__ y_true,
                         const int* __restrict__ tr, const int* __restrict__ va,
                         const int* __restrict__ te, const float* __restrict__ norm,
                         __half* __restrict__ last) {
    int t = blockIdx.x * blockDim.x + threadIdx.x;
    if (t >= NN * 12) return;
    int i = t / 12, ch = (t % 12) * 4;
    int cid = cat_at(i, tr, va, te);
    float4 o;
    if (i < NTR) {
        int yt = y_true[i];
        o.x = (ch + 0 == yt) ? 1.f : 0.f;
        o.y = (ch + 1 == yt) ? 1.f : 0.f;
        o.z = (ch + 2 == yt) ? 1.f : 0.f;
        o.w = (ch + 3 == yt) ? 1.f : 0.f;
    } else {
        // scale >= 0 or +inf or NaN; (isinf || >1000) == (>1000), NaN caught below.
        float s = (sig[0] * (1.0f / NTR)) / rowabs[i];
        if (s > 1000.0f) s = 1.0f;
        float4 e  = h4f(*reinterpret_cast<const uint2*>(se_yall + (size_t)cid * NC + ch));
        float4 ys = *reinterpret_cast<const float4*>(y_soft + (size_t)i * NC + ch);
        o.x = ys.x + s * e.x; if (o.x != o.x) o.x = ys.x;
        o.y = ys.y + s * e.y; if (o.y != o.y) o.y = ys.y;
        o.z = ys.z + s * e.z; if (o.z != o.z) o.z = ys.z;
        o.w = ys.w + s * e.w; if (o.w != o.w) o.w = ys.w;
    }
    float w = norm[cid];
    *reinterpret_cast<uint2*>(se_yall + (size_t)cid * NC + ch) =
        f4h(make_float4(o.x * w, o.y * w, o.z * w, o.w * w));
    float la = 1.0f - ALPHA2;
    *reinterpret_cast<uint2*>(last + (size_t)cid * NC + ch) =
        f4h(make_float4(la * o.x, la * o.y, la * o.z, la * o.w));
}

// out[i] = yin[cat[i]]  (fp16 -> f32)
__global__ void k_outgather(const __half* __restrict__ yin, float* __restrict__ out,
                            const int* __restrict__ tr, const int* __restrict__ va,
                            const int* __restrict__ te) {
    int t = blockIdx.x * blockDim.x + threadIdx.x;
    if (t >= NN * 12) return;
    int i = t / 12, ch = (t % 12) * 4;
    int cid = cat_at(i, tr, va, te);
    float4 v = h4f(*reinterpret_cast<const uint2*>(yin + (size_t)cid * NC + ch));
    *reinterpret_cast<float4*>(out + (size_t)i * NC + ch) = v;
}

extern "C" void kernel_launch(void* const* d_in, const int* in_sizes, int n_in,
                              void* d_out, int out_size, void* d_ws, size_t ws_size,
                              hipStream_t stream) {
    const float* y_soft = (const float*)d_in[0];
    const int*   y_true = (const int*)d_in[1];
    const int*   src    = (const int*)d_in[2];
    const int*   dst    = (const int*)d_in[3];
    const int*   tr     = (const int*)d_in[4];
    const int*   va     = (const int*)d_in[5];
    const int*   te     = (const int*)d_in[6];
    float* out = (float*)d_out;

    char* ws = (char*)d_ws;
    size_t off = 0;
    auto alloc = [&](size_t bytes) -> void* {
        void* p = ws + off;
        off += (bytes + 255) & ~(size_t)255;
        return p;
    };
    __half* A      = (__half*)alloc((size_t)NN * NC * 2);   // 9.6 MB
    __half* B      = (__half*)alloc((size_t)NN * NC * 2);   // 9.6 MB
    __half* last   = (__half*)alloc((size_t)NN * NC * 2);   // 9.6 MB
    int*    csr    = (int*)   alloc((size_t)NE * 4);        // 6.4 MB
    int*    deg3   = (int*)   alloc((size_t)N3 * 4);        // 1.2 MB
    int*    fill3  = (int*)   alloc((size_t)N3 * 4);        // 1.2 MB
    int*    rowp3  = (int*)   alloc((size_t)(N3 + 1) * 4);  // 1.2 MB
    float*  norm   = (float*) alloc((size_t)NN * 4);
    float*  rowabs = (float*) alloc((size_t)NN * 4);
    int*    bsum   = (int*)   alloc((size_t)NB3 * 4);
    float*  sig    = (float*) alloc(256);

    (void)hipMemsetAsync(deg3,  0, (size_t)N3 * 4, stream);
    (void)hipMemsetAsync(fill3, 0, (size_t)N3 * 4, stream);
    (void)hipMemsetAsync(A,     0, (size_t)NN * NC * 2, stream);
    (void)hipMemsetAsync(last,  0, (size_t)NN * NC * 2, stream);
    (void)hipMemsetAsync(sig,   0, 4, stream);

    k_count3 <<<NE / 256, 256, 0, stream>>>(src, dst, deg3);
    k_bsum   <<<NB3, 256, 0, stream>>>(deg3, bsum);
    k_bscan  <<<1, 512, 0, stream>>>(bsum);
    k_scatter<<<NB3, 256, 0, stream>>>(deg3, bsum, rowp3);
    k_norm   <<<(NN + 255) / 256, 256, 0, stream>>>(rowp3, norm);
    k_fill3  <<<NE / 256, 256, 0, stream>>>(src, dst, rowp3, fill3, csr);
    k_error  <<<(NTR * NC) / 256, 256, 0, stream>>>(y_soft, y_true, tr, norm, A, last, sig);

    const int GT = (NN * 12 + 255) / 256;

    // propagation 1: A -> ... -> A (10 layers); last layer unscaled
    __half* cur = A; __half* oth = B;
    for (int l = 0; l < 10; ++l) {
        if (l < 9)
            k_gather<true><<<GT, 256, 0, stream>>>(cur, oth, last, norm, rowp3, csr,
                                                   ALPHA1, -1.f, 1.f);
        else
            k_gather<false><<<GT, 256, 0, stream>>>(cur, oth, last, norm, rowp3, csr,
                                                    ALPHA1, -1.f, 1.f);
        __half* t2 = cur; cur = oth; oth = t2;
    }

    k_rowabs<<<(NN + 255) / 256, 256, 0, stream>>>(A, rowabs);
    // in-place: A := norm .* y_all; last := (1-ALPHA2)*y_all
    k_phaseD<<<GT, 256, 0, stream>>>(A, y_soft, rowabs, sig, y_true,
                                     tr, va, te, norm, last);

    // propagation 2: A -> ... -> A (10 layers); last layer unscaled
    cur = A; oth = B;
    for (int l = 0; l < 10; ++l) {
        if (l < 9)
            k_gather<true><<<GT, 256, 0, stream>>>(cur, oth, last, norm, rowp3, csr,
                                                   ALPHA2, 0.f, 1.f);
        else
            k_gather<false><<<GT, 256, 0, stream>>>(cur, oth, last, norm, rowp3, csr,
                                                    ALPHA2, 0.f, 1.f);
        __half* t2 = cur; cur = oth; oth = t2;
    }

    // d_out[i] = A[cat[i]]
    k_outgather<<<GT, 256, 0, stream>>>(A, out, tr, va, te);
}